// Round 3
// baseline (407.088 us; speedup 1.0000x reference)
//
#include <hip/hip_runtime.h>
#include <cstdint>
#include <utility>

#define SIZE 1349
#define HALF 674
#define N2 (SIZE*SIZE)          // 1,819,801
#define LSIG 1000000
#define NB 8
#define NRINGS 601              // table covers rings 0..600
#define CAP 5376                // max live-ring cell count (<= ~3600 for k<KLIVE)
#define MBUCKET 2048

// ================= compile-time exact ring tables (pure geometry) =================
constexpr long long isqrt_c(long long n) {
    if (n <= 0) return 0;
    long long x = 1;
    while (x * x <= n) x <<= 1;            // ~10 iters
    long long r = 0;
    for (long long b = x; b > 0; b >>= 1) { long long c = r + b; if (c * c <= n) r = c; }
    return r;
}
constexpr uint32_t rowcnt_c(int k, int y) {
    if (k == 0) return (y == 0) ? 1u : 0u;
    long long yy = (long long)y * y;
    long long Bv = (long long)k * (k + 1) - yy;
    if (Bv < 0) return 0u;
    long long h = isqrt_c(Bv); if (h > HALF) h = HALF;
    long long Av = (long long)k * (k - 1) + 1 - yy;
    if (Av <= 0) return (uint32_t)(2 * h + 1);
    long long f = isqrt_c(Av);
    long long lo = (f * f == Av) ? f : f + 1;
    if (lo > h) return 0u;
    return (uint32_t)(2 * (h - lo + 1));
}
constexpr uint32_t ringcnt_c(int k) {
    int ym = (k < HALF) ? k : HALF;
    uint32_t s = 0;
    for (int y = -ym; y <= ym; ++y) s += rowcnt_c(k, y);
    return s;
}
// each RC<K>/OF<K> is its own constant-expression evaluation (stays < 1M steps)
template<int K> struct RC { static constexpr uint32_t v = ringcnt_c(K); };
template<int K> struct OF { static constexpr uint32_t v = OF<K - 1>::v + RC<K - 1>::v; };
template<>      struct OF<0> { static constexpr uint32_t v = 0u; };

struct OffArr { uint32_t a[NRINGS]; };
template<int... I>
constexpr OffArr mkoff(std::integer_sequence<int, I...>) { return {{ OF<I>::v... }}; }

constexpr OffArr HOFF = mkoff(std::make_integer_sequence<int, NRINGS>{});

constexpr int klive_c() {   // first ring whose exclusive offset >= LSIG
    for (int k = 0; k < NRINGS; ++k) if (HOFF.a[k] >= LSIG) return k;
    return NRINGS;
}
constexpr int KLIVE = klive_c();
constexpr uint32_t NTHRESH = (uint32_t)((long long)KLIVE * (KLIVE - 1) + 1);
constexpr uint32_t maxcnt_c() {
    uint32_t m = 0;
    for (int k = 0; k < KLIVE; ++k) { uint32_t c = HOFF.a[k + 1] - HOFF.a[k]; if (c > m) m = c; }
    return m;
}
static_assert(KLIVE < NRINGS - 1, "ring table too small");
static_assert(KLIVE <= HALF, "ymax clamp assumption broken");
static_assert(maxcnt_c() <= CAP, "CAP too small");
static_assert(HOFF.a[KLIVE] < LSIG + CAP, "T2 sizing");

__device__ __constant__ OffArr RING_OFF = mkoff(std::make_integer_sequence<int, NRINGS>{});

// ================= exact integer sqrt (device) =================
__device__ __forceinline__ int isqrt_i(int n) {
    int s = (int)sqrtf((float)n);
    while (s > 0 && s * s > n) s--;
    while ((s + 1) * (s + 1) <= n) s++;
    return s;
}

// Ring k row y: cells with x^2+y^2 in [k(k-1)+1, k(k+1)], |x|<=674.
__device__ __forceinline__ int row_interval(int k, int y, int* xlo, int* xhi) {
    if (k == 0) { if (y == 0) { *xhi = 0; return 1; } return 0; }
    int yy = y * y;
    int B = k * (k + 1) - yy;
    if (B < 0) return 0;
    int h = isqrt_i(B);
    if (h > HALF) h = HALF;
    int A = k * (k - 1) + 1 - yy;
    *xhi = h;
    if (A <= 0) return 1;
    int f = isqrt_i(A);
    int lo = (f * f == A) ? f : f + 1;
    if (lo > h) return 0;
    *xlo = lo;
    return 2;
}

// ================= bucket map: monotone in f32 key bits (unchanged, validated) =================
__device__ __forceinline__ int bucket_of(uint32_t kb, float tt) {
    const float PI_F = 3.14159265358979323846f;
    const float SC = 325.94932f;  // MBUCKET / (2*pi)
    float p2 = __uint_as_float(kb);
    float u = (p2 - tt) + PI_F;   // ~[0, 2pi]
    int b = (int)(u * SC);
    return min(max(b, 0), MBUCKET - 1);
}

// wave-aggregated LDS append: one atomic per wave per call
__device__ __forceinline__ uint32_t lds_append(uint32_t* nT) {
    unsigned long long m = __ballot(1);
    int lane = threadIdx.x & 63;
    int leader = __ffsll(m) - 1;
    uint32_t base = 0;
    if (lane == leader) base = atomicAdd(nT, (uint32_t)__popcll(m));
    base = __shfl(base, leader);
    return base + (uint32_t)__popcll(m & ((1ull << lane) - 1ull));
}

// emit one lattice cell (x,y>=0) of ring k: key math identical to validated rounds
__device__ __forceinline__ void emit(int k, int x, int y, float tt,
                                     uint64_t* T, uint32_t* cnt, uint32_t* nT) {
#pragma clang fp contract(off)
    const float PI_F = 3.14159265358979323846f;
    uint32_t kp, kn = 0;
    if (y == 0) {
        float phi = (x < 0) ? PI_F : 0.0f;   // acos(+-1)*sign(0)=0; +PI if x<0
        kp = __float_as_uint(tt + phi);
    } else {
        int nn = x * x + y * y;
        float rr = sqrtf((float)nn);          // exact int -> CR sqrt
        float q = (float)x / rr;              // CR f32 division
        float ac = (float)::acos((double)q);  // CR float acos (validated R1/R2)
        kp = __float_as_uint(tt + ac);
        kn = __float_as_uint(tt - ac);
    }
    uint32_t gx = (uint32_t)(x + HALF);
    uint32_t gp = (uint32_t)(y + HALF) * SIZE + gx;
    uint32_t p = lds_append(nT);
    T[p] = ((uint64_t)kp << 32) | gp;
    atomicAdd(&cnt[bucket_of(kp, tt)], 1u);
    if (y > 0) {
        uint32_t gn = (uint32_t)(HALF - y) * SIZE + gx;
        uint32_t p2 = lds_append(nT);
        T[p2] = ((uint64_t)kn << 32) | gn;
        atomicAdd(&cnt[bucket_of(kn, tt)], 1u);
    }
}

// ================= pass 1: per-ring ranking (single enumeration, cap-balanced) =================
__global__ __launch_bounds__(1024) void k_rank(uint32_t* __restrict__ rank,
                                               uint64_t* __restrict__ T2) {
#pragma clang fp contract(off)
    __shared__ uint64_t T[CAP];          // 43 KB  (append order)
    __shared__ uint32_t cnt[MBUCKET];    // 8 KB
    __shared__ uint32_t boff[MBUCKET];   // 8 KB
    __shared__ uint32_t ps[1024];        // 4 KB   (total ~63.5 KB -> 2 blocks/CU)
    __shared__ uint32_t nT;
    const float PI_F = 3.14159265358979323846f;
    int k = (KLIVE - 1) - (int)blockIdx.x;   // big rings first -> flat makespan
    int t = threadIdx.x;
    if (k == 0) { if (t == 0) rank[HALF * SIZE + HALF] = 0u; return; }
    uint32_t off = RING_OFF.a[k];
    int n = (int)(RING_OFF.a[k + 1] - off);
    float tt = (2.0f * (float)k) * PI_F;     // same f32 roundings as ref

    cnt[2 * t] = 0u; cnt[2 * t + 1] = 0u;
    if (t == 0) nT = 0u;
    __syncthreads();

    // ---- single enumeration. Tasks: rows y in [0,capy-1] x 2 sides, plus
    // polar-cap (rows y in [capy,k], where x-runs are long) re-tasked as
    // x-columns (each <= ~9 cells) for wave balance. ----
    int capy = (k >= 32) ? (k - 8) : (k + 1);     // k<32: no cap split
    int Bk = k * (k + 1), Ak = k * (k - 1) + 1;
    int nmain = 2 * capy;
    int w = 0, ncap = 0;
    if (capy <= k) { w = isqrt_i(Bk - capy * capy); ncap = 2 * w + 1; }
    int ntot = nmain + ncap;
    for (int task = t; task < ntot; task += 1024) {
        if (task < nmain) {
            int y = task >> 1, side = task & 1;
            int xlo = 0, xhi = 0;
            int kind = row_interval(k, y, &xlo, &xhi);
            if (kind == 0) continue;
            int xs, xe;
            if (side == 0) { xs = -xhi; xe = (kind == 1) ? -1 : -xlo; if (xe < xs) continue; }
            else          { xs = (kind == 1) ? 0 : xlo; xe = xhi; }
            for (int x = xs; x <= xe; ++x) emit(k, x, y, tt, T, cnt, &nT);
        } else {
            int x = (task - nmain) - w;           // cap column, x in [-w,w]
            int xx = x * x;
            int yhi = isqrt_i(Bk - xx);           // <= k
            int aa = Ak - xx;
            int ylo = capy;
            if (aa > 0) {
                int f = isqrt_i(aa);
                int lo = (f * f == aa) ? f : f + 1;
                if (lo > ylo) ylo = lo;
            }
            for (int y = ylo; y <= yhi; ++y) emit(k, x, y, tt, T, cnt, &nT);
        }
    }
    __syncthreads();

    // exclusive scan of cnt[0..2048) via pair-sums + Hillis-Steele over 1024
    uint32_t c0 = cnt[2 * t], c1 = cnt[2 * t + 1];
    uint32_t s = c0 + c1;
    ps[t] = s;
    __syncthreads();
    for (int d = 1; d < 1024; d <<= 1) {
        uint32_t x = (t >= d) ? ps[t - d] : 0u;
        __syncthreads();
        ps[t] += x;
        __syncthreads();
    }
    uint32_t excl = ps[t] - s;
    boff[2 * t] = excl;
    boff[2 * t + 1] = excl + c0;
    __syncthreads();

    // scatter bucket-ordered into global T2 (8 MB scratch, L2-hot); boff[b] -> bucket end
    uint64_t* __restrict__ T2r = T2 + off;
    for (int i = t; i < n; i += 1024) {
        uint64_t v = T[i];
        int b = bucket_of((uint32_t)(v >> 32), tt);
        uint32_t p = atomicAdd(&boff[b], 1u);
        T2r[p] = v;
    }
    __syncthreads();   // drains vmcnt; same-block global visibility

    // rank = ringOff + bucketStart + (# bucket members with smaller (key,idx))
    for (int i = t; i < n; i += 1024) {
        uint64_t v = T[i];
        int b = bucket_of((uint32_t)(v >> 32), tt);
        uint32_t end = boff[b];
        uint32_t start = end - cnt[b];
        uint32_t c = 0;
        for (uint32_t j = start; j < end; ++j) c += (T2r[j] < v) ? 1u : 0u;
        rank[(uint32_t)v] = off + start + c;
    }
}

// ================= pass 2: gather, 16x16 tile, one batch per blockIdx.z =================
typedef float vfloat4 __attribute__((ext_vector_type(4)));

#define TW 16
#define TH 16

__global__ __launch_bounds__(256) void k_gather(const vfloat4* __restrict__ in,
                                                const uint32_t* __restrict__ rank,
                                                vfloat4* __restrict__ out) {
    int tx = threadIdx.x & (TW - 1);
    int ty = threadIdx.x / TW;
    int col = blockIdx.x * TW + tx;
    int row = blockIdx.y * TH + ty;
    int b = blockIdx.z;
    if (col >= SIZE || row >= SIZE) return;
    int g = row * SIZE + col;
    int dx = col - HALF, dy = row - HALF;
    uint32_t nn = (uint32_t)(dx * dx + dy * dy);
    uint32_t q = 0xFFFFFFFFu;
    if (nn < NTHRESH) q = rank[g];   // nn >= NTHRESH => ring >= KLIVE => rank >= LSIG (never written)
    if (q < LSIG) {
        vfloat4 v = in[b * LSIG + (int)q];
        __builtin_nontemporal_store(v, &out[b * N2 + g]);
    } else {
        vfloat4 z = {0.f, 0.f, 0.f, 0.f};
        __builtin_nontemporal_store(z, &out[b * N2 + g]);
    }
}

extern "C" void kernel_launch(void* const* d_in, const int* in_sizes, int n_in,
                              void* d_out, int out_size, void* d_ws, size_t ws_size,
                              hipStream_t stream) {
    const float* in = (const float*)d_in[0];
    float* out = (float*)d_out;
    uint8_t* ws = (uint8_t*)d_ws;

    uint32_t* rank = (uint32_t*)ws;                         // N2*4 = 7.28 MB
    uint64_t* T2   = (uint64_t*)(ws + 16 * 1024 * 1024);    // (LSIG+CAP)*8 = 8.05 MB

    k_rank<<<KLIVE, 1024, 0, stream>>>(rank, T2);

    dim3 gb((SIZE + TW - 1) / TW, (SIZE + TH - 1) / TH, NB);
    k_gather<<<gb, 256, 0, stream>>>((const vfloat4*)in, rank, (vfloat4*)out);
}

// Round 5
// 377.099 us; speedup vs baseline: 1.0795x; 1.0795x over previous
//
#include <hip/hip_runtime.h>
#include <cstdint>
#include <utility>

#define SIZE 1349
#define HALF 674
#define N2 (SIZE*SIZE)          // 1,819,801
#define LSIG 1000000
#define NB 8
#define NRINGS 601              // table covers rings 0..600
#define CAP 5376                // max live-ring cell count (<= ~3600 for k<KLIVE)
#define MBUCKET 2048

// ================= compile-time exact ring tables (pure geometry, validated R3) =================
constexpr long long isqrt_c(long long n) {
    if (n <= 0) return 0;
    long long x = 1;
    while (x * x <= n) x <<= 1;
    long long r = 0;
    for (long long b = x; b > 0; b >>= 1) { long long c = r + b; if (c * c <= n) r = c; }
    return r;
}
constexpr uint32_t rowcnt_c(int k, int y) {
    if (k == 0) return (y == 0) ? 1u : 0u;
    long long yy = (long long)y * y;
    long long Bv = (long long)k * (k + 1) - yy;
    if (Bv < 0) return 0u;
    long long h = isqrt_c(Bv); if (h > HALF) h = HALF;
    long long Av = (long long)k * (k - 1) + 1 - yy;
    if (Av <= 0) return (uint32_t)(2 * h + 1);
    long long f = isqrt_c(Av);
    long long lo = (f * f == Av) ? f : f + 1;
    if (lo > h) return 0u;
    return (uint32_t)(2 * (h - lo + 1));
}
constexpr uint32_t ringcnt_c(int k) {
    int ym = (k < HALF) ? k : HALF;
    uint32_t s = 0;
    for (int y = -ym; y <= ym; ++y) s += rowcnt_c(k, y);
    return s;
}
template<int K> struct RC { static constexpr uint32_t v = ringcnt_c(K); };
template<int K> struct OF { static constexpr uint32_t v = OF<K - 1>::v + RC<K - 1>::v; };
template<>      struct OF<0> { static constexpr uint32_t v = 0u; };

struct OffArr { uint32_t a[NRINGS]; };
template<int... I>
constexpr OffArr mkoff(std::integer_sequence<int, I...>) { return {{ OF<I>::v... }}; }

constexpr OffArr HOFF = mkoff(std::make_integer_sequence<int, NRINGS>{});

constexpr int klive_c() {   // first ring whose exclusive offset >= LSIG
    for (int k = 0; k < NRINGS; ++k) if (HOFF.a[k] >= LSIG) return k;
    return NRINGS;
}
constexpr int KLIVE = klive_c();
constexpr uint32_t NTHRESH = (uint32_t)((long long)KLIVE * (KLIVE - 1) + 1);
constexpr uint32_t maxcnt_c() {
    uint32_t m = 0;
    for (int k = 0; k < KLIVE; ++k) { uint32_t c = HOFF.a[k + 1] - HOFF.a[k]; if (c > m) m = c; }
    return m;
}
static_assert(KLIVE < NRINGS - 1, "ring table too small");
static_assert(KLIVE <= HALF, "ymax clamp assumption broken");
static_assert(maxcnt_c() <= CAP, "CAP too small");

__device__ __constant__ OffArr RING_OFF = mkoff(std::make_integer_sequence<int, NRINGS>{});

// ================= exact integer sqrt (device) =================
__device__ __forceinline__ int isqrt_i(int n) {
    int s = (int)sqrtf((float)n);
    while (s > 0 && s * s > n) s--;
    while ((s + 1) * (s + 1) <= n) s++;
    return s;
}

// Ring k row y: cells with x^2+y^2 in [k(k-1)+1, k(k+1)], |x|<=674.
__device__ __forceinline__ int row_interval(int k, int y, int* xlo, int* xhi) {
    if (k == 0) { if (y == 0) { *xhi = 0; return 1; } return 0; }
    int yy = y * y;
    int B = k * (k + 1) - yy;
    if (B < 0) return 0;
    int h = isqrt_i(B);
    if (h > HALF) h = HALF;
    int A = k * (k - 1) + 1 - yy;
    *xhi = h;
    if (A <= 0) return 1;
    int f = isqrt_i(A);
    int lo = (f * f == A) ? f : f + 1;
    if (lo > h) return 0;
    *xlo = lo;
    return 2;
}

// ================= bucket map: monotone in f32 key bits (validated) =================
__device__ __forceinline__ int bucket_of(uint32_t kb, float tt) {
    const float PI_F = 3.14159265358979323846f;
    const float SC = 325.94932f;  // MBUCKET / (2*pi)
    float p2 = __uint_as_float(kb);
    float u = (p2 - tt) + PI_F;   // ~[0, 2pi]
    int b = (int)(u * SC);
    return min(max(b, 0), MBUCKET - 1);
}

// ================= ring enumeration (round-2 body, verbatim; dual phase) =================
template<int PHASE>
__device__ __forceinline__ void enum_ring(int k, int ymaxv, float tt, int t,
                                          uint32_t* cnt, uint32_t* boff, uint64_t* T) {
#pragma clang fp contract(off)
    const float PI_F = 3.14159265358979323846f;
    int ntask = 2 * (ymaxv + 1);
    for (int task = t; task < ntask; task += 1024) {
        int y = task >> 1, side = task & 1;
        int xlo = 0, xhi = 0;
        int kind = row_interval(k, y, &xlo, &xhi);
        if (kind == 0) continue;
        int xs, xe;
        if (side == 0) {
            xs = -xhi; xe = (kind == 1) ? -1 : -xlo;
            if (xe < xs) continue;
        } else {
            xs = (kind == 1) ? 0 : xlo; xe = xhi;
        }
        for (int x = xs; x <= xe; ++x) {
            uint32_t kp, kn = 0;
            if (y == 0) {
                float phi = (x < 0) ? PI_F : 0.0f;
                kp = __float_as_uint(tt + phi);
            } else {
                int nn = x * x + y * y;
                float rr = sqrtf((float)nn);          // exact int -> CR sqrt
                float q = (float)x / rr;              // CR f32 division
                float ac = (float)::acos((double)q);  // CR float acos (validated R1/R2)
                kp = __float_as_uint(tt + ac);
                kn = __float_as_uint(tt - ac);
            }
            uint32_t gx = (uint32_t)(x + HALF);
            uint32_t gp = (uint32_t)(y + HALF) * SIZE + gx;
            int bp = bucket_of(kp, tt);
            if (PHASE == 0) atomicAdd(&cnt[bp], 1u);
            else { uint32_t p = atomicAdd(&boff[bp], 1u); T[p] = ((uint64_t)kp << 32) | gp; }
            if (y > 0) {
                uint32_t gn = (uint32_t)(HALF - y) * SIZE + gx;
                int bn = bucket_of(kn, tt);
                if (PHASE == 0) atomicAdd(&cnt[bn], 1u);
                else { uint32_t p = atomicAdd(&boff[bn], 1u); T[p] = ((uint64_t)kn << 32) | gn; }
            }
        }
    }
}

// ================= pass 1: per-ring ranking (round-2 structure + const tables) =================
__global__ __launch_bounds__(1024) void k_rank(uint32_t* __restrict__ rank) {
#pragma clang fp contract(off)
    __shared__ uint64_t T[CAP];          // 43 KB
    __shared__ uint32_t cnt[MBUCKET];    // 8 KB
    __shared__ uint32_t boff[MBUCKET];   // 8 KB
    __shared__ uint32_t ps[1024];        // 4 KB  (total 63 KB -> 2 blocks/CU)
    const float PI_F = 3.14159265358979323846f;
    int k = (KLIVE - 1) - (int)blockIdx.x;   // big rings first -> flat makespan
    int t = threadIdx.x;
    if (k == 0) { if (t == 0) rank[HALF * SIZE + HALF] = 0u; return; }
    uint32_t off = RING_OFF.a[k];
    int n = (int)(RING_OFF.a[k + 1] - off);
    int ymaxv = min(k, HALF);
    float tt = (2.0f * (float)k) * PI_F;     // same f32 roundings as ref

    cnt[2 * t] = 0u; cnt[2 * t + 1] = 0u;
    __syncthreads();

    enum_ring<0>(k, ymaxv, tt, t, cnt, boff, T);   // histogram
    __syncthreads();

    uint32_t c0 = cnt[2 * t], c1 = cnt[2 * t + 1];
    uint32_t s = c0 + c1;
    ps[t] = s;
    __syncthreads();
    for (int d = 1; d < 1024; d <<= 1) {
        uint32_t x = (t >= d) ? ps[t - d] : 0u;
        __syncthreads();
        ps[t] += x;
        __syncthreads();
    }
    uint32_t excl = ps[t] - s;
    boff[2 * t] = excl;
    boff[2 * t + 1] = excl + c0;
    __syncthreads();

    enum_ring<1>(k, ymaxv, tt, t, cnt, boff, T);   // scatter; boff[b] -> bucket end
    __syncthreads();

    for (int i = t; i < n; i += 1024) {
        uint64_t v = T[i];
        uint32_t kb = (uint32_t)(v >> 32);
        int b = bucket_of(kb, tt);
        uint32_t end = boff[b];
        uint32_t start = end - cnt[b];
        uint32_t c = 0;
        for (uint32_t j = start; j < end; ++j) c += (T[j] < v) ? 1u : 0u;
        rank[(uint32_t)v] = off + start + c;
    }
}

// ================= pass 2: gather, 32x32 tile, 4 cells/thread (MLP=4), batch on z ==========
// Thread (tx,ty) handles rows ty+{0,8,16,24} of the tile at column tx:
// 4 independent rank loads issued together, then 4 independent in-loads, then 4 NT stores.
// Write segments stay 512B contiguous per row (32 lanes x 16B). 32-wide tiling measured
// >=15us better than 16-wide (R2 vs R3).
typedef float vfloat4 __attribute__((ext_vector_type(4)));

__global__ __launch_bounds__(256) void k_gather(const vfloat4* __restrict__ in,
                                                const uint32_t* __restrict__ rank,
                                                vfloat4* __restrict__ out) {
    int tx = threadIdx.x & 31;
    int ty = threadIdx.x >> 5;
    int col = blockIdx.x * 32 + tx;
    if (col >= SIZE) return;
    int row0 = blockIdx.y * 32 + ty;
    int b = blockIdx.z;
    const vfloat4* __restrict__ inb = in + (size_t)b * LSIG;
    vfloat4* __restrict__ outb = out + (size_t)b * N2;
    int dx = col - HALF;

    uint32_t q[4]; int g[4]; bool ok[4];
#pragma unroll
    for (int j = 0; j < 4; ++j) {
        int row = row0 + 8 * j;
        ok[j] = (row < SIZE);
        g[j] = row * SIZE + col;
        int dy = row - HALF;
        uint32_t nn = (uint32_t)(dx * dx + dy * dy);
        q[j] = 0xFFFFFFFFu;
        if (ok[j] && nn < NTHRESH) q[j] = rank[g[j]];  // outside: rank never written (poison-safe)
    }
    vfloat4 v[4];
#pragma unroll
    for (int j = 0; j < 4; ++j) {
        vfloat4 z = {0.f, 0.f, 0.f, 0.f};
        v[j] = z;
        if (q[j] < LSIG) v[j] = inb[(int)q[j]];
    }
#pragma unroll
    for (int j = 0; j < 4; ++j)
        if (ok[j]) __builtin_nontemporal_store(v[j], &outb[g[j]]);
}

extern "C" void kernel_launch(void* const* d_in, const int* in_sizes, int n_in,
                              void* d_out, int out_size, void* d_ws, size_t ws_size,
                              hipStream_t stream) {
    const float* in = (const float*)d_in[0];
    float* out = (float*)d_out;
    uint8_t* ws = (uint8_t*)d_ws;

    uint32_t* rank = (uint32_t*)ws;   // N2*4 = 7.28 MB

    k_rank<<<KLIVE, 1024, 0, stream>>>(rank);

    dim3 gb((SIZE + 31) / 32, (SIZE + 31) / 32, NB);
    k_gather<<<gb, 256, 0, stream>>>((const vfloat4*)in, rank, (vfloat4*)out);
}